// Round 1
// baseline (885.348 us; speedup 1.0000x reference)
//
#include <hip/hip_runtime.h>
#include <math.h>

#define N 2048
#define NN (N * N)
#define NSTEPS 15

// Constants matching the reference (computed in double, rounded to f32 like
// JAX's weak-typed python-scalar * f32-array promotion).
constexpr double DXd = 14.0 / 2047.0;           // (14.0)/(nx+1), nx=2046
constexpr float DX2f = (float)(DXd * DXd);      // divisor used by reference
constexpr float DTf  = (float)(0.032 / 16.0);   // 0.002
constexpr float HDTf = (float)(0.5 * (0.032 / 16.0)); // 0.001

// ---------------------------------------------------------------------------
// k1_v = DT * (lap(u) - sin(u));  lap zero on the ghost ring.
__global__ void k1_kernel(const float* __restrict__ u, float* __restrict__ k1) {
    int j = blockIdx.x * blockDim.x + threadIdx.x;
    int i = blockIdx.y;
    int idx = i * N + j;
    float c = u[idx];
    float lap = 0.0f;
    if (i > 0 && i < N - 1 && j > 0 && j < N - 1) {
        lap = (u[idx + N] + u[idx - N] - 2.0f * c) / DX2f
            + (u[idx + 1] + u[idx - 1] - 2.0f * c) / DX2f;
    }
    k1[idx] = DTf * (lap - sinf(c));
}

// ---------------------------------------------------------------------------
// a3 = u + 0.5*DT*(v + 0.5*k1) evaluated on the fly at the 5 stencil points.
// k3_v = DT * (lap(a3) - sin(a3))
__global__ void k3_kernel(const float* __restrict__ u, const float* __restrict__ v,
                          const float* __restrict__ k1, float* __restrict__ k3) {
    int j = blockIdx.x * blockDim.x + threadIdx.x;
    int i = blockIdx.y;
    int idx = i * N + j;
    float a3c = u[idx] + HDTf * (v[idx] + 0.5f * k1[idx]);
    float lap = 0.0f;
    if (i > 0 && i < N - 1 && j > 0 && j < N - 1) {
        float a3n = u[idx - N] + HDTf * (v[idx - N] + 0.5f * k1[idx - N]);
        float a3s = u[idx + N] + HDTf * (v[idx + N] + 0.5f * k1[idx + N]);
        float a3w = u[idx - 1] + HDTf * (v[idx - 1] + 0.5f * k1[idx - 1]);
        float a3e = u[idx + 1] + HDTf * (v[idx + 1] + 0.5f * k1[idx + 1]);
        lap = (a3s + a3n - 2.0f * a3c) / DX2f + (a3e + a3w - 2.0f * a3c) / DX2f;
    }
    k3[idx] = DTf * (lap - sinf(a3c));
}

// ---------------------------------------------------------------------------
// Computes k2 (a2 = u + 0.5*DT*v) and k4 (a4 = u + DT*(v + k3)) inline,
// then the RK4 combination. Full grid (ring gets lap=0 → v corners evolve
// exactly like the reference; u ring is overwritten by bc_kernel anyway).
__global__ void combine_kernel(const float* __restrict__ u, const float* __restrict__ v,
                               const float* __restrict__ k1v, const float* __restrict__ k3v,
                               float* __restrict__ un, float* __restrict__ vn) {
    int j = blockIdx.x * blockDim.x + threadIdx.x;
    int i = blockIdx.y;
    int idx = i * N + j;
    float uc = u[idx], vc = v[idx];
    float k1c = k1v[idx], k3c = k3v[idx];
    float a2c = uc + HDTf * vc;
    float a4c = uc + DTf * (vc + k3c);
    float lap2 = 0.0f, lap4 = 0.0f;
    if (i > 0 && i < N - 1 && j > 0 && j < N - 1) {
        float a2n = u[idx - N] + HDTf * v[idx - N];
        float a2s = u[idx + N] + HDTf * v[idx + N];
        float a2w = u[idx - 1] + HDTf * v[idx - 1];
        float a2e = u[idx + 1] + HDTf * v[idx + 1];
        lap2 = (a2s + a2n - 2.0f * a2c) / DX2f + (a2e + a2w - 2.0f * a2c) / DX2f;
        float a4n = u[idx - N] + DTf * (v[idx - N] + k3v[idx - N]);
        float a4s = u[idx + N] + DTf * (v[idx + N] + k3v[idx + N]);
        float a4w = u[idx - 1] + DTf * (v[idx - 1] + k3v[idx - 1]);
        float a4e = u[idx + 1] + DTf * (v[idx + 1] + k3v[idx + 1]);
        lap4 = (a4s + a4n - 2.0f * a4c) / DX2f + (a4e + a4w - 2.0f * a4c) / DX2f;
    }
    float k2c = DTf * (lap2 - sinf(a2c));
    float k4c = DTf * (lap4 - sinf(a4c));

    float k1u = DTf * vc;
    float k2u = DTf * (vc + 0.5f * k1c);
    float k3u = DTf * (vc + 0.5f * k2c);
    float k4u = DTf * (vc + k3c);

    un[idx] = uc + (k1u + 2.0f * k2u + 2.0f * k3u + k4u) / 6.0f;
    vn[idx] = vc + (k1c + 2.0f * k2c + 2.0f * k3c + k4c) / 6.0f;
}

// ---------------------------------------------------------------------------
// Boundary conditions, reproducing the reference's sequential .at[].set():
//   rows first (interior cols), then full columns (which see post-row values).
// All reads below are of interior values written by combine_kernel, so there
// is no intra-kernel RAW hazard.
__global__ void bc_kernel(float* __restrict__ un, float* __restrict__ vn) {
    int t = blockIdx.x * blockDim.x + threadIdx.x;
    if (t >= 1 && t <= N - 2) {
        // u rows from adjacent interior rows
        un[0 * N + t]       = un[1 * N + t];
        un[(N - 1) * N + t] = un[(N - 2) * N + t];
        // u columns from adjacent interior cols (interior rows only here)
        un[t * N + 0]       = un[t * N + 1];
        un[t * N + (N - 1)] = un[t * N + (N - 2)];
        // v edges zero (corners untouched)
        vn[0 * N + t] = 0.0f;
        vn[(N - 1) * N + t] = 0.0f;
        vn[t * N + 0] = 0.0f;
        vn[t * N + (N - 1)] = 0.0f;
    } else if (t == 0) {
        // u corners: column-op reads post-row-op values
        un[0]                         = un[1 * N + 1];
        un[N - 1]                     = un[1 * N + (N - 2)];
        un[(N - 1) * N + 0]           = un[(N - 2) * N + 1];
        un[(N - 1) * N + (N - 1)]     = un[(N - 2) * N + (N - 2)];
    }
}

// ---------------------------------------------------------------------------
extern "C" void kernel_launch(void* const* d_in, const int* in_sizes, int n_in,
                              void* d_out, int out_size, void* d_ws, size_t ws_size,
                              hipStream_t stream) {
    const float* u0 = (const float*)d_in[0];
    const float* v0 = (const float*)d_in[1];
    float* out_u = (float*)d_out;          // [N*N]
    float* out_v = out_u + NN;             // [N*N]

    float* ws = (float*)d_ws;
    float* wu = ws;                        // ping-pong u
    float* wv = ws + (size_t)NN;           // ping-pong v
    float* k1 = ws + 2 * (size_t)NN;       // k1_v buffer
    float* k3 = ws + 3 * (size_t)NN;       // k3_v buffer

    dim3 blk(256, 1, 1);
    dim3 grd(N / 256, N, 1);

    const float* us = u0;
    const float* vs = v0;
    for (int s = 0; s < NSTEPS; ++s) {
        float *ud, *vd;
        if ((s & 1) == 0) { ud = out_u; vd = out_v; }  // odd-numbered steps → d_out; s=14 (last) lands here
        else             { ud = wu;    vd = wv;    }
        k1_kernel<<<grd, blk, 0, stream>>>(us, k1);
        k3_kernel<<<grd, blk, 0, stream>>>(us, vs, k1, k3);
        combine_kernel<<<grd, blk, 0, stream>>>(us, vs, k1, k3, ud, vd);
        bc_kernel<<<dim3(N / 256), dim3(256), 0, stream>>>(ud, vd);
        us = ud; vs = vd;
    }
}